// Round 8
// baseline (168.059 us; speedup 1.0000x reference)
//
#include <hip/hip_runtime.h>
#include <hip/hip_bf16.h>

#define BSZ 256
#define ADIM 128
#define HID 512
#define MT 64          // pair-rows per block
#define LDH 520        // padded LDS row stride in bf16 elements

typedef __attribute__((ext_vector_type(8))) short short8;
typedef __attribute__((ext_vector_type(4))) short bfx4;
typedef __attribute__((ext_vector_type(4))) float float4_t;

__device__ inline short f32_to_bf16_bits(float f) {
    union { float f; unsigned u; } v; v.f = f;
    unsigned u = v.u;
    unsigned r = u + 0x7FFFu + ((u >> 16) & 1u);   // RNE
    return (short)(r >> 16);
}
__device__ inline float bf16_bits_to_f32(short s) {
    union { unsigned u; float f; } v;
    v.u = ((unsigned)(unsigned short)s) << 16;
    return v.f;
}

// ---------------- prep (256 blocks x 512 threads) ----------------
// blocks [0,64):    hx = x@Wx + b0   (4 rows per block)
// blocks [64,128):  hy = y@Wy        (4 rows per block)
// blocks [128,192): W1p = fragment-packed bf16 of W1 (64x64 tile per block)
// blocks [192,256): W2p = fragment-packed bf16 of W2
// Packed: Wp[((s*32+g)*64 + lane)*8 + j] = W[s*32 + (lane>>4)*8 + j][g*16 + (lane&15)]
// == the A-operand fragment W'[n][k] for n-subtile g, k-step s (and also the
// B-operand fragment of the same tile) -> main-kernel load is lane*16B coalesced.
__global__ __launch_bounds__(512) void prep_kernel(
        const float* __restrict__ x, const float* __restrict__ y,
        const float* __restrict__ Wx, const float* __restrict__ Wy,
        const float* __restrict__ b0, const float* __restrict__ W1,
        const float* __restrict__ W2,
        float* __restrict__ hx, float* __restrict__ hy,
        short* __restrict__ W1p, short* __restrict__ W2p) {
    __shared__ float lds[64 * 65];
    const int tid = threadIdx.x;
    const int bid = blockIdx.x;

    if (bid < 128) {
        const bool isX = bid < 64;
        const int i0 = (isX ? bid : bid - 64) * 4;
        const float* src = isX ? x : y;
        const float* W   = isX ? Wx : Wy;
        float* dst       = isX ? hx : hy;

        lds[tid] = src[i0 * ADIM + tid];
        __syncthreads();

        const int h = tid;
        float s0 = 0.f, s1 = 0.f, s2 = 0.f, s3 = 0.f;
        const float* wcol = W + h;
        #pragma unroll 8
        for (int k = 0; k < ADIM; ++k) {
            float w = wcol[k * HID];
            s0 = fmaf(lds[k], w, s0);
            s1 = fmaf(lds[ADIM + k], w, s1);
            s2 = fmaf(lds[2 * ADIM + k], w, s2);
            s3 = fmaf(lds[3 * ADIM + k], w, s3);
        }
        float bb = isX ? b0[h] : 0.f;
        dst[(i0 + 0) * HID + h] = s0 + bb;
        dst[(i0 + 1) * HID + h] = s1 + bb;
        dst[(i0 + 2) * HID + h] = s2 + bb;
        dst[(i0 + 3) * HID + h] = s3 + bb;
    } else {
        const int tb = bid - 128;
        const bool is1 = tb < 64;
        const int t8 = is1 ? tb : tb - 64;
        const float* Wsrc = is1 ? W1 : W2;
        short* Wdst = is1 ? W1p : W2p;
        const int k0 = (t8 >> 3) * 64;      // source k block
        const int n0 = (t8 & 7) * 64;       // source n block

        #pragma unroll
        for (int i = 0; i < 8; ++i) {
            int r = (tid >> 6) + i * 8;     // k within tile
            int c = tid & 63;               // n within tile (coalesced)
            lds[c * 65 + r] = Wsrc[(k0 + r) * HID + n0 + c];
        }
        __syncthreads();

        const int local_s = tid >> 8;           // 0..1
        const int g_local = (tid >> 6) & 3;     // 0..3
        const int lane    = tid & 63;
        const int quad    = lane >> 4;
        const int lq      = lane & 15;
        const int s_glob  = (t8 >> 3) * 2 + local_s;   // 0..15
        const int g_glob  = (t8 & 7) * 4 + g_local;    // 0..31

        const float* srcp = lds + (g_local * 16 + lq) * 65 + local_s * 32 + quad * 8;
        short8 v;
        #pragma unroll
        for (int j = 0; j < 8; ++j) v[j] = f32_to_bf16_bits(srcp[j]);
        *(short8*)(Wdst + ((s_glob * 32 + g_glob) * 64 + lane) * 8) = v;
    }
}

// ---------------- fused layer, role-swapped MFMA ----------------
// D'[n][m] = sum_k W'[n][k] * h[m][k]:  A-operand = W fragment (global, packed),
// B-operand = h fragment (LDS; identical addresses to the old A-read).
// C-layout: lane(quad,lq) holds rows n=quad*4+r, col m=lq -> epilogue writes
// 4 consecutive n as one ds_write_b64 at hs[m][n..n+3].
__device__ __forceinline__ void gemm_layer(short* __restrict__ hs,
                                           const short* __restrict__ Wp,
                                           const float* __restrict__ bias,
                                           int wave, int lane) {
    const int quad = lane >> 4;
    const int lq = lane & 15;
    const int n0 = wave * 64;

    // bias along n: 4 consecutive values per lane per nb
    float4_t bv[4];
    #pragma unroll
    for (int nb = 0; nb < 4; ++nb)
        bv[nb] = *(const float4_t*)(bias + n0 + nb * 16 + quad * 4);

    float4_t acc[4][4];   // [nb][mb]
    #pragma unroll
    for (int nb = 0; nb < 4; ++nb)
        #pragma unroll
        for (int mb = 0; mb < 4; ++mb)
            acc[nb][mb] = (float4_t){0.f, 0.f, 0.f, 0.f};

    const short* pb = Wp + wave * 2048 + lane * 8;     // + nb*512 + s*16384
    const short* hbase = hs + lq * LDH + quad * 8;     // + mb*16*LDH + s*32

    short8 wf[2][4];
    #pragma unroll
    for (int nb = 0; nb < 4; ++nb)
        wf[0][nb] = *(const short8*)(pb + nb * 512);

    #pragma unroll
    for (int s = 0; s < 16; ++s) {
        const int cur = s & 1;
        if (s < 15) {
            #pragma unroll
            for (int nb = 0; nb < 4; ++nb)
                wf[cur ^ 1][nb] = *(const short8*)(pb + (s + 1) * 16384 + nb * 512);
        }
        short8 hf[4];
        #pragma unroll
        for (int mb = 0; mb < 4; ++mb)
            hf[mb] = *(const short8*)(hbase + mb * 16 * LDH + s * 32);
        #pragma unroll
        for (int nb = 0; nb < 4; ++nb)
            #pragma unroll
            for (int mb = 0; mb < 4; ++mb)
                acc[nb][mb] = __builtin_amdgcn_mfma_f32_16x16x32_bf16(
                    wf[cur][nb], hf[mb], acc[nb][mb], 0, 0, 0);
    }

    __syncthreads();   // all reads of hs complete before overwrite

    #pragma unroll
    for (int nb = 0; nb < 4; ++nb) {
        #pragma unroll
        for (int mb = 0; mb < 4; ++mb) {
            bfx4 v;
            #pragma unroll
            for (int r = 0; r < 4; ++r)
                v[r] = f32_to_bf16_bits(fmaxf(acc[nb][mb][r] + bv[nb][r], 0.f));
            *(bfx4*)(hs + (mb * 16 + lq) * LDH + n0 + nb * 16 + quad * 4) = v;
        }
    }
    __syncthreads();
}

__global__ __launch_bounds__(512, 4) void critic_kernel(
    const float* __restrict__ hx, const float* __restrict__ hy,
    const short* __restrict__ W1p, const short* __restrict__ W2p,
    const float* __restrict__ b1, const float* __restrict__ b2,
    const float* __restrict__ W3, const float* __restrict__ b3,
    float* __restrict__ out) {
    __shared__ short hs[MT * LDH];   // 66,560 B
    __shared__ float psum[512];      // 2,048 B  (total 68,608 -> 2 blocks/CU)

    const int tid = threadIdx.x;
    const int wave = tid >> 6;
    const int lane = tid & 63;

    const int i0 = (blockIdx.x >> 5) * 8;
    const int j0 = (blockIdx.x & 31) * 8;

    // ---- h0 = relu(hx[i] + hy[j]) bf16 in LDS (b0 folded into hx) ----
    #pragma unroll
    for (int e = tid; e < MT * 64; e += 512) {
        int r = e >> 6;
        int ko = (e & 63) * 8;
        int ti = r >> 3, tj = r & 7;
        const float4_t* px = (const float4_t*)(hx + (i0 + ti) * HID + ko);
        const float4_t* py = (const float4_t*)(hy + (j0 + tj) * HID + ko);
        float4_t a0 = px[0], a1 = px[1];
        float4_t c0 = py[0], c1 = py[1];
        short8 v;
        #pragma unroll
        for (int u = 0; u < 4; ++u) v[u]     = f32_to_bf16_bits(fmaxf(a0[u] + c0[u], 0.f));
        #pragma unroll
        for (int u = 0; u < 4; ++u) v[4 + u] = f32_to_bf16_bits(fmaxf(a1[u] + c1[u], 0.f));
        *(short8*)(hs + r * LDH + ko) = v;
    }
    __syncthreads();

    gemm_layer(hs, W1p, b1, wave, lane);   // h1 = relu(h0 @ W1 + b1)
    gemm_layer(hs, W2p, b2, wave, lane);   // h2 = relu(h1 @ W2 + b2)

    // ---- final: out = h2 @ W3 + b3 ----
    {
        int r = tid >> 3;
        int oc = (tid & 7) * 64;
        const short* hrow = hs + r * LDH + oc;
        float s = 0.f;
        #pragma unroll
        for (int k = 0; k < 64; k += 8) {
            short8 v = *(const short8*)(hrow + k);
            #pragma unroll
            for (int u = 0; u < 8; ++u)
                s = fmaf(bf16_bits_to_f32(v[u]), W3[oc + k + u], s);
        }
        psum[tid] = s;
    }
    __syncthreads();
    if (tid < 64) {
        float s = b3[0];
        #pragma unroll
        for (int o = 0; o < 8; ++o) s += psum[tid * 8 + o];
        int ti = tid >> 3, tj = tid & 7;
        out[(i0 + ti) * BSZ + (j0 + tj)] = s;
    }
}

extern "C" void kernel_launch(void* const* d_in, const int* in_sizes, int n_in,
                              void* d_out, int out_size, void* d_ws, size_t ws_size,
                              hipStream_t stream) {
    const float* x  = (const float*)d_in[0];
    const float* y  = (const float*)d_in[1];
    const float* Wx = (const float*)d_in[2];
    const float* Wy = (const float*)d_in[3];
    const float* b0 = (const float*)d_in[4];
    const float* W1 = (const float*)d_in[5];
    const float* b1 = (const float*)d_in[6];
    const float* W2 = (const float*)d_in[7];
    const float* b2 = (const float*)d_in[8];
    const float* W3 = (const float*)d_in[9];
    const float* b3 = (const float*)d_in[10];
    float* out = (float*)d_out;

    char* ws = (char*)d_ws;
    float* hx  = (float*)(ws);
    float* hy  = (float*)(ws + 512 * 1024);
    short* W1p = (short*)(ws + 1024 * 1024);
    short* W2p = (short*)(ws + 1536 * 1024);

    prep_kernel<<<256, 512, 0, stream>>>(x, y, Wx, Wy, b0, W1, W2, hx, hy, W1p, W2p);
    critic_kernel<<<1024, 512, 0, stream>>>(hx, hy, W1p, W2p, b1, b2, W3, b3, out);
}

// Round 9
// 148.537 us; speedup vs baseline: 1.1314x; 1.1314x over previous
//
#include <hip/hip_runtime.h>
#include <hip/hip_bf16.h>

#define BSZ 256
#define ADIM 128
#define HID 512
#define MT 64          // pair-rows per block
#define LDH 520        // padded LDS row stride in bf16 elements

typedef __attribute__((ext_vector_type(8))) short short8;
typedef __attribute__((ext_vector_type(4))) short bfx4;
typedef __attribute__((ext_vector_type(4))) float float4_t;

__device__ inline short f32_to_bf16_bits(float f) {
    union { float f; unsigned u; } v; v.f = f;
    unsigned u = v.u;
    unsigned r = u + 0x7FFFu + ((u >> 16) & 1u);   // RNE
    return (short)(r >> 16);
}
__device__ inline float bf16_bits_to_f32(short s) {
    union { unsigned u; float f; } v;
    v.u = ((unsigned)(unsigned short)s) << 16;
    return v.f;
}

// ---------------- prep (256 blocks x 512 threads) ----------------
// blocks [0,64):    hx = x@Wx + b0   (4 rows per block)
// blocks [64,128):  hy = y@Wy        (4 rows per block)
// blocks [128,192): W1p = fragment-packed bf16 of W1 (64x64 tile per block)
// blocks [192,256): W2p = fragment-packed bf16 of W2
// Packed: Wp[((s*32+g)*64 + lane)*8 + j] = W[s*32 + (lane>>4)*8 + j][g*16 + (lane&15)]
__global__ __launch_bounds__(512) void prep_kernel(
        const float* __restrict__ x, const float* __restrict__ y,
        const float* __restrict__ Wx, const float* __restrict__ Wy,
        const float* __restrict__ b0, const float* __restrict__ W1,
        const float* __restrict__ W2,
        float* __restrict__ hx, float* __restrict__ hy,
        short* __restrict__ W1p, short* __restrict__ W2p) {
    __shared__ float lds[64 * 65];
    const int tid = threadIdx.x;
    const int bid = blockIdx.x;

    if (bid < 128) {
        const bool isX = bid < 64;
        const int i0 = (isX ? bid : bid - 64) * 4;
        const float* src = isX ? x : y;
        const float* W   = isX ? Wx : Wy;
        float* dst       = isX ? hx : hy;

        lds[tid] = src[i0 * ADIM + tid];
        __syncthreads();

        const int h = tid;
        float s0 = 0.f, s1 = 0.f, s2 = 0.f, s3 = 0.f;
        const float* wcol = W + h;
        #pragma unroll 8
        for (int k = 0; k < ADIM; ++k) {
            float w = wcol[k * HID];
            s0 = fmaf(lds[k], w, s0);
            s1 = fmaf(lds[ADIM + k], w, s1);
            s2 = fmaf(lds[2 * ADIM + k], w, s2);
            s3 = fmaf(lds[3 * ADIM + k], w, s3);
        }
        float bb = isX ? b0[h] : 0.f;
        dst[(i0 + 0) * HID + h] = s0 + bb;
        dst[(i0 + 1) * HID + h] = s1 + bb;
        dst[(i0 + 2) * HID + h] = s2 + bb;
        dst[(i0 + 3) * HID + h] = s3 + bb;
    } else {
        const int tb = bid - 128;
        const bool is1 = tb < 64;
        const int t8 = is1 ? tb : tb - 64;
        const float* Wsrc = is1 ? W1 : W2;
        short* Wdst = is1 ? W1p : W2p;
        const int k0 = (t8 >> 3) * 64;      // source k block
        const int n0 = (t8 & 7) * 64;       // source n block

        #pragma unroll
        for (int i = 0; i < 8; ++i) {
            int r = (tid >> 6) + i * 8;     // k within tile
            int c = tid & 63;               // n within tile (coalesced)
            lds[c * 65 + r] = Wsrc[(k0 + r) * HID + n0 + c];
        }
        __syncthreads();

        const int local_s = tid >> 8;           // 0..1
        const int g_local = (tid >> 6) & 3;     // 0..3
        const int lane    = tid & 63;
        const int quad    = lane >> 4;
        const int lq      = lane & 15;
        const int s_glob  = (t8 >> 3) * 2 + local_s;   // 0..15
        const int g_glob  = (t8 & 7) * 4 + g_local;    // 0..31

        const float* srcp = lds + (g_local * 16 + lq) * 65 + local_s * 32 + quad * 8;
        short8 v;
        #pragma unroll
        for (int j = 0; j < 8; ++j) v[j] = f32_to_bf16_bits(srcp[j]);
        *(short8*)(Wdst + ((s_glob * 32 + g_glob) * 64 + lane) * 8) = v;
    }
}

// ---------------- fused layer, role-swapped MFMA ----------------
// D'[n][m] = sum_k W'[n][k] * h[m][k]:  A-operand = W fragment (global, packed),
// B-operand = h fragment (LDS). C-layout: lane(quad,lq) holds rows n=quad*4+r,
// col m=lq -> epilogue writes 4 consecutive n as one ds_write_b64.
// Bias is loaded AFTER the k-loop: keeps in-loop live set <= 128 regs (no spill).
__device__ __forceinline__ void gemm_layer(short* __restrict__ hs,
                                           const short* __restrict__ Wp,
                                           const float* __restrict__ bias,
                                           int wave, int lane) {
    const int quad = lane >> 4;
    const int lq = lane & 15;
    const int n0 = wave * 64;

    float4_t acc[4][4];   // [nb][mb]
    #pragma unroll
    for (int nb = 0; nb < 4; ++nb)
        #pragma unroll
        for (int mb = 0; mb < 4; ++mb)
            acc[nb][mb] = (float4_t){0.f, 0.f, 0.f, 0.f};

    const short* pb = Wp + wave * 2048 + lane * 8;     // + nb*512 + s*16384
    const short* hbase = hs + lq * LDH + quad * 8;     // + mb*16*LDH + s*32

    short8 wf[2][4];
    #pragma unroll
    for (int nb = 0; nb < 4; ++nb)
        wf[0][nb] = *(const short8*)(pb + nb * 512);

    #pragma unroll
    for (int s = 0; s < 16; ++s) {
        const int cur = s & 1;
        if (s < 15) {
            #pragma unroll
            for (int nb = 0; nb < 4; ++nb)
                wf[cur ^ 1][nb] = *(const short8*)(pb + (s + 1) * 16384 + nb * 512);
        }
        short8 hf[4];
        #pragma unroll
        for (int mb = 0; mb < 4; ++mb)
            hf[mb] = *(const short8*)(hbase + mb * 16 * LDH + s * 32);
        #pragma unroll
        for (int nb = 0; nb < 4; ++nb)
            #pragma unroll
            for (int mb = 0; mb < 4; ++mb)
                acc[nb][mb] = __builtin_amdgcn_mfma_f32_16x16x32_bf16(
                    wf[cur][nb], hf[mb], acc[nb][mb], 0, 0, 0);
    }

    __syncthreads();   // all reads of hs complete before overwrite

    // bias along n: 4 consecutive values per lane per nb (epilogue-only live range)
    float4_t bv[4];
    #pragma unroll
    for (int nb = 0; nb < 4; ++nb)
        bv[nb] = *(const float4_t*)(bias + n0 + nb * 16 + quad * 4);

    #pragma unroll
    for (int nb = 0; nb < 4; ++nb) {
        #pragma unroll
        for (int mb = 0; mb < 4; ++mb) {
            bfx4 v;
            #pragma unroll
            for (int r = 0; r < 4; ++r)
                v[r] = f32_to_bf16_bits(fmaxf(acc[nb][mb][r] + bv[nb][r], 0.f));
            *(bfx4*)(hs + (mb * 16 + lq) * LDH + n0 + nb * 16 + quad * 4) = v;
        }
    }
    __syncthreads();
}

__global__ __launch_bounds__(512, 4) void critic_kernel(
    const float* __restrict__ hx, const float* __restrict__ hy,
    const short* __restrict__ W1p, const short* __restrict__ W2p,
    const float* __restrict__ b1, const float* __restrict__ b2,
    const float* __restrict__ W3, const float* __restrict__ b3,
    float* __restrict__ out) {
    __shared__ short hs[MT * LDH];   // 66,560 B
    __shared__ float psum[512];      // 2,048 B  (total 68,608 -> 2 blocks/CU)

    const int tid = threadIdx.x;
    const int wave = tid >> 6;
    const int lane = tid & 63;

    const int i0 = (blockIdx.x >> 5) * 8;
    const int j0 = (blockIdx.x & 31) * 8;

    // ---- h0 = relu(hx[i] + hy[j]) bf16 in LDS (b0 folded into hx) ----
    #pragma unroll
    for (int e = tid; e < MT * 64; e += 512) {
        int r = e >> 6;
        int ko = (e & 63) * 8;
        int ti = r >> 3, tj = r & 7;
        const float4_t* px = (const float4_t*)(hx + (i0 + ti) * HID + ko);
        const float4_t* py = (const float4_t*)(hy + (j0 + tj) * HID + ko);
        float4_t a0 = px[0], a1 = px[1];
        float4_t c0 = py[0], c1 = py[1];
        short8 v;
        #pragma unroll
        for (int u = 0; u < 4; ++u) v[u]     = f32_to_bf16_bits(fmaxf(a0[u] + c0[u], 0.f));
        #pragma unroll
        for (int u = 0; u < 4; ++u) v[4 + u] = f32_to_bf16_bits(fmaxf(a1[u] + c1[u], 0.f));
        *(short8*)(hs + r * LDH + ko) = v;
    }
    __syncthreads();

    gemm_layer(hs, W1p, b1, wave, lane);   // h1 = relu(h0 @ W1 + b1)
    gemm_layer(hs, W2p, b2, wave, lane);   // h2 = relu(h1 @ W2 + b2)

    // ---- final: out = h2 @ W3 + b3 ----
    {
        int r = tid >> 3;
        int oc = (tid & 7) * 64;
        const short* hrow = hs + r * LDH + oc;
        float s = 0.f;
        #pragma unroll
        for (int k = 0; k < 64; k += 8) {
            short8 v = *(const short8*)(hrow + k);
            #pragma unroll
            for (int u = 0; u < 8; ++u)
                s = fmaf(bf16_bits_to_f32(v[u]), W3[oc + k + u], s);
        }
        psum[tid] = s;
    }
    __syncthreads();
    if (tid < 64) {
        float s = b3[0];
        #pragma unroll
        for (int o = 0; o < 8; ++o) s += psum[tid * 8 + o];
        int ti = tid >> 3, tj = tid & 7;
        out[(i0 + ti) * BSZ + (j0 + tj)] = s;
    }
}

extern "C" void kernel_launch(void* const* d_in, const int* in_sizes, int n_in,
                              void* d_out, int out_size, void* d_ws, size_t ws_size,
                              hipStream_t stream) {
    const float* x  = (const float*)d_in[0];
    const float* y  = (const float*)d_in[1];
    const float* Wx = (const float*)d_in[2];
    const float* Wy = (const float*)d_in[3];
    const float* b0 = (const float*)d_in[4];
    const float* W1 = (const float*)d_in[5];
    const float* b1 = (const float*)d_in[6];
    const float* W2 = (const float*)d_in[7];
    const float* b2 = (const float*)d_in[8];
    const float* W3 = (const float*)d_in[9];
    const float* b3 = (const float*)d_in[10];
    float* out = (float*)d_out;

    char* ws = (char*)d_ws;
    float* hx  = (float*)(ws);
    float* hy  = (float*)(ws + 512 * 1024);
    short* W1p = (short*)(ws + 1024 * 1024);
    short* W2p = (short*)(ws + 1536 * 1024);

    prep_kernel<<<256, 512, 0, stream>>>(x, y, Wx, Wy, b0, W1, W2, hx, hy, W1p, W2p);
    critic_kernel<<<1024, 512, 0, stream>>>(hx, hy, W1p, W2p, b1, b2, W3, b3, out);
}